// Round 1
// baseline (450.422 us; speedup 1.0000x reference)
//
#include <hip/hip_runtime.h>
#include <math.h>

#define EPSQ 1e-7f
#define TDIM 2000
#define CDIM 128
#define LDIM 200
#define SDIM 401   // 2*L+1
#define SPL  7     // states per lane; 64*7=448 >= 401
#define SENTE (-(1 << 30))

// One wave64 per batch item. Lane owns states s = 7*lane .. 7*lane+6.
// Alphas kept in linear domain, per-lane block-floating-point scale 2^E.

__device__ __forceinline__ void renorm_reconcile(float a[SPL], int& E, float& fprev, int lane) {
    float m = fmaxf(fmaxf(fmaxf(a[0], a[1]), fmaxf(a[2], a[3])),
                    fmaxf(fmaxf(a[4], a[5]), a[6]));
    bool zero = (m == 0.f);
    int e = ((__float_as_int(m) >> 23) & 0xff) - 127;
    int S_self = zero ? SENTE : (E + e);
    int S1 = __shfl_up(S_self, 1, 64);
    int S2 = __shfl_up(S_self, 2, 64);
    if (lane < 1) S1 = SENTE;
    if (lane < 2) S2 = SENTE;
    int E_new = max(S_self, S1);          // this lane's new scale
    int E_prevnew = max(S1, S2);          // left neighbor's new scale (its max(S_self, its S1))
    // rescale own values: g = 2^(E - E_new), exact power of two
    int dg = E - E_new;                   // <= 127 always (dg <= -e)
    float g = (zero || dg < -126) ? 0.f : __int_as_float((dg + 127) << 23);
#pragma unroll
    for (int j = 0; j < SPL; ++j) a[j] *= g;
    E = E_new;
    // factor applied to borrowed neighbor values for the next 4 steps
    int df = E_prevnew - E_new;
    bool fz = (E_prevnew <= SENTE / 2) || (df < -126);
    if (df > 126) df = 126;               // only reachable when neighbor is dead (borrowed==0)
    fprev = fz ? 0.f : __int_as_float((df + 127) << 23);
}

// One recursion step. BR/WB are ring indices (compile-time in the unrolled main
// loop). Reads row t from qbuf[BR] (written last step), writes row t+1 from the
// prefetch register P[WB] into qbuf[WB], and issues the load for row t+5.
#define CTC_STEP(BR, WB, LOADROW)                                              \
    do {                                                                       \
        asm volatile("s_waitcnt lgkmcnt(0)" ::: "memory"); /* prev write ok */ \
        {                                                                      \
            float2 w = P[WB];                                                  \
            w.x += EPSQ; w.y += EPSQ;                                          \
            *(float2*)(&qbuf[WB][lane * 2]) = w;                               \
        }                                                                      \
        {                                                                      \
            int r = (LOADROW);                                                 \
            if (r > Tbm1) r = Tbm1;                                            \
            P[WB] = rp[r * (CDIM / 2) + lane];                                 \
        }                                                                      \
        float p6 = __shfl_up(a[6], 1, 64) * fprev;                             \
        float p5 = __shfl_up(a[5], 1, 64) * fprev;                             \
        const float* qr = qbuf[BR];                                            \
        float q0 = qr[cls[0]], q1 = qr[cls[1]], q2 = qr[cls[2]];               \
        float q3 = qr[cls[3]], q4 = qr[cls[4]], q5 = qr[cls[5]];               \
        float q6 = qr[cls[6]];                                                 \
        float n0 = fmaf(skipf[0], p5, a[0] + p6) * q0;                         \
        float n1 = fmaf(skipf[1], p6, a[1] + a[0]) * q1;                       \
        float n2 = fmaf(skipf[2], a[0], a[2] + a[1]) * q2;                     \
        float n3 = fmaf(skipf[3], a[1], a[3] + a[2]) * q3;                     \
        float n4 = fmaf(skipf[4], a[2], a[4] + a[3]) * q4;                     \
        float n5 = fmaf(skipf[5], a[3], a[5] + a[4]) * q5;                     \
        float n6 = fmaf(skipf[6], a[4], a[6] + a[5]) * q6;                     \
        a[0] = n0; a[1] = n1; a[2] = n2; a[3] = n3;                            \
        a[4] = n4; a[5] = n5; a[6] = n6;                                       \
    } while (0)

__global__ __launch_bounds__(64, 1) void ctc_kernel(
    const float* __restrict__ y_pred,    // [B,T,C] softmax probs
    const int* __restrict__ labels,      // [B,L]
    const int* __restrict__ feat_lens,   // [B]
    const int* __restrict__ label_lens,  // [B]
    float* __restrict__ out)             // [B]
{
    const int b = blockIdx.x;
    const int lane = threadIdx.x;

    __shared__ float qbuf[4][CDIM];   // emission-prob ring (q = p + EPS)
    __shared__ int   labs[LDIM];
    __shared__ float cap_v[2];
    __shared__ int   cap_e[2];

    // subsampled frame count
    int f = feat_lens[b];
    f = (f + 1) >> 1;
    f = (f + 1) >> 1;
    const int Tb = f;                 // in [1000, 2000] <= TDIM
    const int Tbm1 = Tb - 1;
    const int llen = label_lens[b];
    const int i1 = 2 * llen - 1, i2 = 2 * llen;

    const float2* rp = (const float2*)(y_pred + (size_t)b * TDIM * CDIM);

    // issue prefetches for rows 0..3 early
    float2 P[4];
#pragma unroll
    for (int k = 0; k < 4; ++k) {
        int r = (k > Tbm1) ? Tbm1 : k;
        P[k] = rp[r * (CDIM / 2) + lane];
    }

    // stage labels
    const int* labrow = labels + b * LDIM;
    for (int i = lane; i < LDIM; i += 64) labs[i] = labrow[i];
    asm volatile("s_waitcnt lgkmcnt(0)" ::: "memory");

    // per-lane per-state constants (blank = 127; labels are in [0,126])
    int cls[SPL];
    float skipf[SPL];
    const int s0 = lane * SPL;
#pragma unroll
    for (int j = 0; j < SPL; ++j) {
        int s = s0 + j;
        int c = CDIM - 1;
        float sk = 0.f;
        if (s < SDIM && (s & 1)) {
            int k = s >> 1;
            c = labs[k];
            if (k >= 1 && labs[k] != labs[k - 1]) sk = 1.f;
        }
        cls[j] = c;
        skipf[j] = sk;
    }

    // prologue: rows 0 and 1 into LDS ring, refill P[0],P[1] with rows 4,5
    {
        float2 w = P[0]; w.x += EPSQ; w.y += EPSQ;
        *(float2*)(&qbuf[0][lane * 2]) = w;
        int r = (4 > Tbm1) ? Tbm1 : 4;
        P[0] = rp[r * (CDIM / 2) + lane];
    }
    {
        float2 w = P[1]; w.x += EPSQ; w.y += EPSQ;
        *(float2*)(&qbuf[1][lane * 2]) = w;
        int r = (5 > Tbm1) ? Tbm1 : 5;
        P[1] = rp[r * (CDIM / 2) + lane];
    }
    asm volatile("s_waitcnt lgkmcnt(0)" ::: "memory");

    // alpha init at t=0: alpha[0] = q0[blank], alpha[1] = q0[labels[0]]
    float a[SPL];
#pragma unroll
    for (int j = 0; j < SPL; ++j) a[j] = 0.f;
    if (lane == 0) {
        a[0] = qbuf[0][CDIM - 1];
        a[1] = qbuf[0][cls[1]];
    }
    int E = 0;
    float fprev = 0.f;

    // main loop: groups of 4 steps, t0 = 1, 5, 9, ...  (t0 & 3 == 1 invariant)
    int t = 1;
    while (t + 3 <= Tbm1) {
        renorm_reconcile(a, E, fprev, lane);
        CTC_STEP(1, 2, t + 5);
        CTC_STEP(2, 3, t + 6);
        CTC_STEP(3, 0, t + 7);
        CTC_STEP(0, 1, t + 8);
        t += 4;
    }

    // remainder (0..3 steps), reload rows directly
    if (t <= Tbm1) {
        renorm_reconcile(a, E, fprev, lane);
        for (; t <= Tbm1; ++t) {
            int br = t & 3;
            float2 w = rp[t * (CDIM / 2) + lane];
            w.x += EPSQ; w.y += EPSQ;
            *(float2*)(&qbuf[br][lane * 2]) = w;
            asm volatile("s_waitcnt lgkmcnt(0)" ::: "memory");
            float p6 = __shfl_up(a[6], 1, 64) * fprev;
            float p5 = __shfl_up(a[5], 1, 64) * fprev;
            const float* qr = qbuf[br];
            float q0 = qr[cls[0]], q1 = qr[cls[1]], q2 = qr[cls[2]];
            float q3 = qr[cls[3]], q4 = qr[cls[4]], q5 = qr[cls[5]];
            float q6 = qr[cls[6]];
            float n0 = fmaf(skipf[0], p5, a[0] + p6) * q0;
            float n1 = fmaf(skipf[1], p6, a[1] + a[0]) * q1;
            float n2 = fmaf(skipf[2], a[0], a[2] + a[1]) * q2;
            float n3 = fmaf(skipf[3], a[1], a[3] + a[2]) * q3;
            float n4 = fmaf(skipf[4], a[2], a[4] + a[3]) * q4;
            float n5 = fmaf(skipf[5], a[3], a[5] + a[4]) * q5;
            float n6 = fmaf(skipf[6], a[4], a[6] + a[5]) * q6;
            a[0] = n0; a[1] = n1; a[2] = n2; a[3] = n3;
            a[4] = n4; a[5] = n5; a[6] = n6;
        }
    }

    // capture: ll = logaddexp(alpha[i1], alpha[i2]) at t = Tb-1
    {
        const int l1 = i1 / SPL, j1 = i1 % SPL;
        const int l2 = i2 / SPL, j2 = i2 % SPL;
        if (lane == l1) {
            float v = 0.f;
#pragma unroll
            for (int j = 0; j < SPL; ++j)
                if (j == j1) v = a[j];
            cap_v[0] = v; cap_e[0] = E;
        }
        if (lane == l2) {
            float v = 0.f;
#pragma unroll
            for (int j = 0; j < SPL; ++j)
                if (j == j2) v = a[j];
            cap_v[1] = v; cap_e[1] = E;
        }
        asm volatile("s_waitcnt lgkmcnt(0)" ::: "memory");
        if (lane == 0) {
            float v1 = cap_v[0], v2 = cap_v[1];
            double t1 = (v1 > 0.f) ? (log2((double)v1) + (double)cap_e[0]) : -3e38;
            double t2 = (v2 > 0.f) ? (log2((double)v2) + (double)cap_e[1]) : -3e38;
            double m = fmax(t1, t2);
            if (m <= -2.9e38) {
                out[b] = 1.0e30f;  // matches reference's -NEG magnitude
            } else {
                double s = exp2(t1 - m) + exp2(t2 - m);
                double ll2 = m + log2(s);
                out[b] = (float)(-ll2 * 0.69314718055994530942);
            }
        }
    }
}

extern "C" void kernel_launch(void* const* d_in, const int* in_sizes, int n_in,
                              void* d_out, int out_size, void* d_ws, size_t ws_size,
                              hipStream_t stream) {
    const float* y_pred    = (const float*)d_in[0];
    const int*   labels    = (const int*)d_in[1];
    const int*   feat_lens = (const int*)d_in[2];
    const int*   label_lens= (const int*)d_in[3];
    float* out = (float*)d_out;
    const int B = in_sizes[2];  // 128
    ctc_kernel<<<B, 64, 0, stream>>>(y_pred, labels, feat_lens, label_lens, out);
}

// Round 2
// 364.612 us; speedup vs baseline: 1.2353x; 1.2353x over previous
//
#include <hip/hip_runtime.h>
#include <math.h>

#define EPSQ 1e-7f
#define TDIM 2000
#define CDIM 128
#define LDIM 200
#define SDIM 401   // 2*L+1
#define SPL  7     // states per lane; 64*7=448 >= 401
#define SENTE (-(1 << 30))
#define NP 8       // prefetch row-pairs in flight (16 rows)
#define NR 4       // LDS ring row-pairs (8 rows, 4 KB)

// wave_shr:1 DPP — shift value to lane+1, lane0 reads 0 (bound_ctrl).
__device__ __forceinline__ float dppf(float x) {
    return __int_as_float(__builtin_amdgcn_update_dpp(
        0, __float_as_int(x), 0x138, 0xf, 0xf, true));
}
__device__ __forceinline__ int dppi(int x) {
    return __builtin_amdgcn_update_dpp(0, x, 0x138, 0xf, 0xf, true);
}

// Per-lane block-floating-point renorm + neighbor scale reconcile (every 4 steps).
__device__ __forceinline__ void renorm_reconcile(float a[SPL], int& E, float& fprev, int lane) {
    float m = fmaxf(fmaxf(fmaxf(a[0], a[1]), fmaxf(a[2], a[3])),
                    fmaxf(fmaxf(a[4], a[5]), a[6]));
    bool zero = (m == 0.f);
    int e = ((__float_as_int(m) >> 23) & 0xff) - 127;
    int S_self = zero ? SENTE : (E + e);
    int S1 = dppi(S_self);
    if (lane == 0) S1 = SENTE;
    int S2 = dppi(S1);
    if (lane == 0) S2 = SENTE;
    int E_new = max(S_self, S1);
    int E_prevnew = max(S1, S2);
    int dg = E - E_new;
    float g = (zero || dg < -126) ? 0.f : __int_as_float((dg + 127) << 23);
#pragma unroll
    for (int j = 0; j < SPL; ++j) a[j] *= g;
    E = E_new;
    int df = E_prevnew - E_new;
    bool fz = (E_prevnew <= SENTE / 2) || (df < -126);
    if (df > 126) df = 126;
    fprev = fz ? 0.f : __int_as_float((df + 127) << 23);
}

// One recursion step. QS = q-register slot (compile-time). If WR: stage the
// next row-pair from PF[PSLOT] into LDS ring slot WSLOT and refill PF.
// Gathers for row tcur+4 (ring slot GS, parity GPAR) are issued AFTER the
// alpha update (they retarget q[QS], 4-step latency budget).
#define CTC_STEP(QS, WR, WSLOT, PSLOT, GS, GPAR, TOFF)                          \
  {                                                                             \
    const int tcur = t + (TOFF);                                                \
    if (WR) {                                                                   \
      float4 w = PF[PSLOT];                                                     \
      w.x += EPSQ; w.y += EPSQ; w.z += EPSQ; w.w += EPSQ;                       \
      *(float4*)&ring[(WSLOT) * 256 + lane * 4] = w;                            \
      int pl = (tcur + 20) >> 1;                                                \
      if (pl > pmax) pl = pmax;                                                 \
      PF[PSLOT] = rp4[pl * 64 + lane];                                          \
    }                                                                           \
    float p6 = dppf(a[6]) * fprev;                                              \
    float p5 = dppf(a[5]) * fprev;                                              \
    float n0 = fmaf(skipf[0], p5,   a[0] + p6)   * q[QS][0];                    \
    float n1 = fmaf(skipf[1], p6,   a[1] + a[0]) * q[QS][1];                    \
    float n2 = fmaf(skipf[2], a[0], a[2] + a[1]) * q[QS][2];                    \
    float n3 = fmaf(skipf[3], a[1], a[3] + a[2]) * q[QS][3];                    \
    float n4 = fmaf(skipf[4], a[2], a[4] + a[3]) * q[QS][4];                    \
    float n5 = fmaf(skipf[5], a[3], a[5] + a[4]) * q[QS][5];                    \
    float n6 = fmaf(skipf[6], a[4], a[6] + a[5]) * q[QS][6];                    \
    a[0]=n0; a[1]=n1; a[2]=n2; a[3]=n3; a[4]=n4; a[5]=n5; a[6]=n6;              \
    _Pragma("unroll")                                                           \
    for (int j = 0; j < SPL; ++j)                                               \
      q[QS][j] = ring[(GS) * 256 + (GPAR) * 128 + cls[j]];                      \
    if (tcur == Tbm1) {                                                         \
      float v1 = 0.f, v2 = 0.f;                                                 \
      _Pragma("unroll")                                                         \
      for (int j = 0; j < SPL; ++j) { if (j == j1) v1 = a[j]; if (j == j2) v2 = a[j]; } \
      if (lane == l1) { cap1 = v1; cape1 = E; }                                 \
      if (lane == l2) { cap2 = v2; cape2 = E; }                                 \
    }                                                                           \
  }

// 4 steps per block, renorm at block top. bb = block index mod 4 (compile-time).
#define CTC_BLOCK(bb)                                                           \
  renorm_reconcile(a, E, fprev, lane);                                          \
  CTC_STEP(1, false, 0, 0,                 ((2*(bb)+2)&3), 1, 4*(bb)+0);        \
  CTC_STEP(2, true,  ((2*(bb)+3)&3), ((2*(bb)+3)&7), ((2*(bb)+3)&3), 0, 4*(bb)+1); \
  CTC_STEP(3, false, 0, 0,                 ((2*(bb)+3)&3), 1, 4*(bb)+2);        \
  CTC_STEP(0, true,  ((2*(bb)+4)&3), ((2*(bb)+4)&7), ((2*(bb)+4)&3), 0, 4*(bb)+3);

__global__ __launch_bounds__(64, 1) void ctc_kernel(
    const float* __restrict__ y_pred,    // [B,T,C] softmax probs
    const int* __restrict__ labels,      // [B,L]
    const int* __restrict__ feat_lens,   // [B]
    const int* __restrict__ label_lens,  // [B]
    float* __restrict__ out)             // [B]
{
    const int b = blockIdx.x;
    const int lane = threadIdx.x;

    __shared__ float ring[NR * 256];  // 4 row-pairs (8 rows of C=128), q = p+EPS
    __shared__ int   labs[LDIM];

    int f = feat_lens[b];
    f = (f + 1) >> 1;
    f = (f + 1) >> 1;
    const int Tbm1 = f - 1;
    const int pmax = Tbm1 >> 1;
    const int llen = label_lens[b];
    const int i1 = 2 * llen - 1, i2 = 2 * llen;
    const int l1 = i1 / SPL, j1 = i1 % SPL;
    const int l2 = i2 / SPL, j2 = i2 % SPL;

    const float4* rp4 = (const float4*)(y_pred + (size_t)b * TDIM * CDIM);

    // prefetch row-pairs 0..7 (rows 0..15, clamped)
    float4 PF[NP];
#pragma unroll
    for (int p = 0; p < NP; ++p) {
        int pl = (p > pmax) ? pmax : p;
        PF[p] = rp4[pl * 64 + lane];
    }

    // stage labels, build per-lane class/skip tables
    const int* labrow = labels + b * LDIM;
    for (int i = lane; i < LDIM; i += 64) labs[i] = labrow[i];
    asm volatile("s_waitcnt lgkmcnt(0)" ::: "memory");

    int cls[SPL];
    float skipf[SPL];
    const int s0 = lane * SPL;
#pragma unroll
    for (int j = 0; j < SPL; ++j) {
        int s = s0 + j;
        int c = CDIM - 1;
        float sk = 0.f;
        if (s < SDIM && (s & 1)) {
            int k = s >> 1;
            c = labs[k];
            if (k >= 1 && labs[k] != labs[k - 1]) sk = 1.f;
        }
        cls[j] = c;
        skipf[j] = sk;
    }

    // stage pairs 0,1,2 (rows 0..5) into ring; refill PF[0..2] with pairs 8..10
#pragma unroll
    for (int p = 0; p < 3; ++p) {
        float4 w = PF[p];
        w.x += EPSQ; w.y += EPSQ; w.z += EPSQ; w.w += EPSQ;
        *(float4*)&ring[p * 256 + lane * 4] = w;
        int pl = (p + 8 > pmax) ? pmax : (p + 8);
        PF[p] = rp4[pl * 64 + lane];
    }

    // gather rows 0..3 into q[0..3]
    float q[4][SPL];
#pragma unroll
    for (int j = 0; j < SPL; ++j) {
        q[0][j] = ring[0 * 256 + 0 * 128 + cls[j]];
        q[1][j] = ring[0 * 256 + 1 * 128 + cls[j]];
        q[2][j] = ring[1 * 256 + 0 * 128 + cls[j]];
        q[3][j] = ring[1 * 256 + 1 * 128 + cls[j]];
    }

    // alpha init at t=0 (lane0: state0=blank -> q[0][0], state1=labels[0] -> q[0][1])
    float a[SPL];
#pragma unroll
    for (int j = 0; j < SPL; ++j) a[j] = 0.f;
    if (lane == 0) { a[0] = q[0][0]; a[1] = q[0][1]; }
    int E = 0;
    float fprev = 0.f;

    float cap1 = 0.f, cap2 = 0.f;
    int cape1 = 0, cape2 = 0;

    if (Tbm1 == 0) {  // degenerate: capture at t=0
        float v1 = 0.f, v2 = 0.f;
#pragma unroll
        for (int j = 0; j < SPL; ++j) { if (j == j1) v1 = a[j]; if (j == j2) v2 = a[j]; }
        if (lane == l1) { cap1 = v1; cape1 = E; }
        if (lane == l2) { cap2 = v2; cape2 = E; }
    }

    // refill q[0] with row 4 (pair 2, parity 0)
#pragma unroll
    for (int j = 0; j < SPL; ++j) q[0][j] = ring[2 * 256 + 0 * 128 + cls[j]];

    // main loop: 16 steps per iteration; ring/PF/q slots all compile-time.
    // Steps past Tbm1 compute garbage (clamped rows), capture already taken.
    for (int t = 1; t <= Tbm1; t += 16) {
        CTC_BLOCK(0)
        CTC_BLOCK(1)
        CTC_BLOCK(2)
        CTC_BLOCK(3)
    }

    // epilogue: ll = logaddexp over captured states, in log2 domain via double
    float c1 = __shfl(cap1, l1);
    int   e1 = __shfl(cape1, l1);
    float c2 = __shfl(cap2, l2);
    int   e2 = __shfl(cape2, l2);
    if (lane == 0) {
        double t1 = (c1 > 0.f) ? (log2((double)c1) + (double)e1) : -3e38;
        double t2 = (c2 > 0.f) ? (log2((double)c2) + (double)e2) : -3e38;
        double m = fmax(t1, t2);
        if (m <= -2.9e38) {
            out[b] = 1.0e30f;
        } else {
            double s = exp2(t1 - m) + exp2(t2 - m);
            double ll2 = m + log2(s);
            out[b] = (float)(-ll2 * 0.69314718055994530942);
        }
    }
}

extern "C" void kernel_launch(void* const* d_in, const int* in_sizes, int n_in,
                              void* d_out, int out_size, void* d_ws, size_t ws_size,
                              hipStream_t stream) {
    const float* y_pred     = (const float*)d_in[0];
    const int*   labels     = (const int*)d_in[1];
    const int*   feat_lens  = (const int*)d_in[2];
    const int*   label_lens = (const int*)d_in[3];
    float* out = (float*)d_out;
    const int B = in_sizes[2];  // 128
    ctc_kernel<<<B, 64, 0, stream>>>(y_pred, labels, feat_lens, label_lens, out);
}

// Round 3
// 273.286 us; speedup vs baseline: 1.6482x; 1.3342x over previous
//
#include <hip/hip_runtime.h>
#include <math.h>

#define EPSQ 1e-7f
#define TDIM 2000
#define CDIM 128
#define LDIM 200
#define SDIM 401
#define SPL  7
#define SENTE (-(1 << 30))

// smem int-index map
#define RINGA 0        // 8192 ints (32KB): 64 rows x 128 floats, row r -> r&63
#define RINGB 8192     // 8192 ints (32KB)
#define LABSI 16384    // 200 ints
#define PRODA 16592
#define CONSA 16593
#define PRODB 16594
#define CONSB 16595
#define BDONE 16596
#define BVALS 16608    // 448 floats (beta result, lane*7+j)
#define BEXPI 17056    // 64 ints (beta scale exp)
#define SMEMN 17120    // 68480 B

__device__ __forceinline__ float dpp_shr_f(float x) { // lane i <- lane i-1, lane0 <- 0
    return __int_as_float(__builtin_amdgcn_update_dpp(0, __float_as_int(x), 0x138, 0xf, 0xf, true));
}
__device__ __forceinline__ int dpp_shr_i(int x) {
    return __builtin_amdgcn_update_dpp(0, x, 0x138, 0xf, 0xf, true);
}
__device__ __forceinline__ float dpp_shl_f(float x) { // lane i <- lane i+1, lane63 <- 0
    return __int_as_float(__builtin_amdgcn_update_dpp(0, __float_as_int(x), 0x130, 0xf, 0xf, true));
}
__device__ __forceinline__ int dpp_shl_i(int x) {
    return __builtin_amdgcn_update_dpp(0, x, 0x130, 0xf, 0xf, true);
}

// ---- alpha renorm (verified round 1/2): per-lane BFP, neighbor = lane-1
__device__ __forceinline__ void renorm_alpha(float a[SPL], int& E, float& fprev, int lane) {
    float mx = fmaxf(fmaxf(fmaxf(a[0], a[1]), fmaxf(a[2], a[3])),
                     fmaxf(fmaxf(a[4], a[5]), a[6]));
    bool zero = (mx == 0.f);
    int e = ((__float_as_int(mx) >> 23) & 0xff) - 127;
    int S_self = zero ? SENTE : (E + e);
    int S1 = dpp_shr_i(S_self);
    if (lane == 0) S1 = SENTE;
    int S2 = dpp_shr_i(S1);
    if (lane == 0) S2 = SENTE;
    int E_new = max(S_self, S1);
    int E_prevnew = max(S1, S2);
    int dg = E - E_new;
    float g = (zero || dg < -126) ? 0.f : __int_as_float((dg + 127) << 23);
#pragma unroll
    for (int j = 0; j < SPL; ++j) a[j] *= g;
    E = E_new;
    int df = E_prevnew - E_new;
    bool fz = (E_prevnew <= SENTE / 2) || (df < -126);
    if (df > 126) df = 126;
    fprev = fz ? 0.f : __int_as_float((df + 127) << 23);
}

// ---- beta renorm: mirror, neighbor = lane+1
__device__ __forceinline__ void renorm_beta(float b[SPL], int& E, float& fnext, int lane) {
    float mx = fmaxf(fmaxf(fmaxf(b[0], b[1]), fmaxf(b[2], b[3])),
                     fmaxf(fmaxf(b[4], b[5]), b[6]));
    bool zero = (mx == 0.f);
    int e = ((__float_as_int(mx) >> 23) & 0xff) - 127;
    int S_self = zero ? SENTE : (E + e);
    int S1 = dpp_shl_i(S_self);
    if (lane == 63) S1 = SENTE;
    int S2 = dpp_shl_i(S1);
    if (lane == 63) S2 = SENTE;
    int E_new = max(S_self, S1);
    int E_nextnew = max(S1, S2);
    int dg = E - E_new;
    float g = (zero || dg < -126) ? 0.f : __int_as_float((dg + 127) << 23);
#pragma unroll
    for (int j = 0; j < SPL; ++j) b[j] *= g;
    E = E_new;
    int df = E_nextnew - E_new;
    bool fz = (E_nextnew <= SENTE / 2) || (df < -126);
    if (df > 126) df = 126;
    fnext = fz ? 0.f : __int_as_float((df + 127) << 23);
}

// alpha step: consumes row t+TOFF (slot (t+TOFF)&3 = (1+TOFF)&3 since t%16==1),
// then issues 2-ahead gathers for row t+TOFF+2 into slot (3+TOFF)&3.
#define A_STEP(TOFF) do {                                                     \
    float p6 = dpp_shr_f(a[6]) * fprev;                                       \
    float p5 = dpp_shr_f(a[5]) * fprev;                                       \
    float n0 = fmaf(skipf[0], p5,   a[0] + p6)   * q[(1+(TOFF))&3][0];        \
    float n1 = fmaf(skipf[1], p6,   a[1] + a[0]) * q[(1+(TOFF))&3][1];        \
    float n2 = fmaf(skipf[2], a[0], a[2] + a[1]) * q[(1+(TOFF))&3][2];        \
    float n3 = fmaf(skipf[3], a[1], a[3] + a[2]) * q[(1+(TOFF))&3][3];        \
    float n4 = fmaf(skipf[4], a[2], a[4] + a[3]) * q[(1+(TOFF))&3][4];        \
    float n5 = fmaf(skipf[5], a[3], a[5] + a[4]) * q[(1+(TOFF))&3][5];        \
    float n6 = fmaf(skipf[6], a[4], a[6] + a[5]) * q[(1+(TOFF))&3][6];        \
    a[0]=n0; a[1]=n1; a[2]=n2; a[3]=n3; a[4]=n4; a[5]=n5; a[6]=n6;            \
    if (t + (TOFF) == m) {                                                    \
        _Pragma("unroll")                                                     \
        for (int j = 0; j < SPL; ++j) ac[j] = a[j];                           \
        Eac = E;                                                              \
    }                                                                         \
    {   const int rr = ((t + (TOFF) + 2) & 63) << 7;                          \
        _Pragma("unroll")                                                     \
        for (int j = 0; j < SPL; ++j)                                         \
            q[(3+(TOFF))&3][j] = ringA[rr + cls[j]];                          \
    }                                                                         \
} while (0);

// beta step index s+SOFF consumes row t0-(s+SOFF), slot (SOFF)&3 (s%16==0);
// gathers row t0-(s+SOFF+2) into slot (2+SOFF)&3.
#define B_STEP(SOFF) do {                                                     \
    float c0 = bb[0]*q[(SOFF)&3][0], c1 = bb[1]*q[(SOFF)&3][1];               \
    float c2 = bb[2]*q[(SOFF)&3][2], c3 = bb[3]*q[(SOFF)&3][3];               \
    float c4 = bb[4]*q[(SOFF)&3][4], c5 = bb[5]*q[(SOFF)&3][5];               \
    float c6 = bb[6]*q[(SOFF)&3][6];                                          \
    float cn0 = dpp_shl_f(c0) * fnext;                                        \
    float cn1 = dpp_shl_f(c1) * fnext;                                        \
    bb[0] = fmaf(skb[0], c2, c0 + c1);                                        \
    bb[1] = fmaf(skb[1], c3, c1 + c2);                                        \
    bb[2] = fmaf(skb[2], c4, c2 + c3);                                        \
    bb[3] = fmaf(skb[3], c5, c3 + c4);                                        \
    bb[4] = fmaf(skb[4], c6, c4 + c5);                                        \
    bb[5] = fmaf(skb[5], cn0, c5 + c6);                                       \
    bb[6] = fmaf(skb[6], cn1, c6 + cn0);                                      \
    if (s + (SOFF) == scap) {                                                 \
        _Pragma("unroll")                                                     \
        for (int j = 0; j < SPL; ++j) bc[j] = bb[j];                          \
        Ebc = E;                                                              \
    }                                                                         \
    {   const int rr = ((t0 - s - (SOFF) - 2) & 63) << 7;                     \
        _Pragma("unroll")                                                     \
        for (int j = 0; j < SPL; ++j)                                         \
            q[(2+(SOFF))&3][j] = ringB[rr + cls[j]];                          \
    }                                                                         \
} while (0);

__global__ void __launch_bounds__(256, 1)
__attribute__((amdgpu_waves_per_eu(1, 1)))
ctc_kernel(const float* __restrict__ y_pred,
           const int* __restrict__ labels,
           const int* __restrict__ feat_lens,
           const int* __restrict__ label_lens,
           float* __restrict__ out)
{
    __shared__ int smem[SMEMN];
    float* smf = (float*)smem;
    volatile int* vsm = (volatile int*)smem;

    const int b = blockIdx.x;
    const int tid = threadIdx.x;
    const int lane = tid & 63;
    const int wv = tid >> 6;

    int f = feat_lens[b];
    f = (f + 1) >> 1; f = (f + 1) >> 1;
    const int Tbm1 = f - 1;
    const int m = f >> 1;             // alpha: steps 1..m; beta: rows Tbm1..m+1

    if (tid < 8) smem[PRODA + tid] = 0;
    const int* labrow = labels + b * LDIM;
    for (int i = tid; i < LDIM; i += 256) smem[LABSI + i] = labrow[i];
    __syncthreads();

    const float4* rp4 = (const float4*)(y_pred + (size_t)b * TDIM * CDIM);

    if (wv == 2) {
        // ---------------- producer A: pairs 0..pend ascending ----------------
        const int pend = (m + 18) >> 1;
        int p = 0;
        while (p <= pend) {
            while (vsm[CONSA] + 32 < p + 8) __builtin_amdgcn_s_sleep(2);
            asm volatile("" ::: "memory");
            float4 w[8];
#pragma unroll
            for (int i = 0; i < 8; ++i) {
                int pi = p + i; if (pi > pend) pi = pend;
                w[i] = rp4[pi * 64 + lane];
            }
#pragma unroll
            for (int i = 0; i < 8; ++i) {
                int pi = p + i; if (pi > pend) pi = pend;
                float4 x = w[i];
                x.x += EPSQ; x.y += EPSQ; x.z += EPSQ; x.w += EPSQ;
                *(float4*)&smf[RINGA + (pi & 31) * 256 + lane * 4] = x;
            }
            asm volatile("s_waitcnt lgkmcnt(0)" ::: "memory");
            vsm[PRODA] = p + 8;
            p += 8;
        }
        return;
    }
    if (wv == 3) {
        // ---------------- producer B: pairs pstart..pl descending ------------
        const int pstart = Tbm1 >> 1;
        int pl = (m - 18) >> 1; if (pl < 0) pl = 0;
        const int kend = pstart - pl;
        int k = 0;
        while (k <= kend) {
            while (vsm[CONSB] + 32 < k + 8) __builtin_amdgcn_s_sleep(2);
            asm volatile("" ::: "memory");
            float4 w[8];
#pragma unroll
            for (int i = 0; i < 8; ++i) {
                int ki = k + i; if (ki > kend) ki = kend;
                w[i] = rp4[(pstart - ki) * 64 + lane];
            }
#pragma unroll
            for (int i = 0; i < 8; ++i) {
                int ki = k + i; if (ki > kend) ki = kend;
                float4 x = w[i];
                x.x += EPSQ; x.y += EPSQ; x.z += EPSQ; x.w += EPSQ;
                *(float4*)&smf[RINGB + ((pstart - ki) & 31) * 256 + lane * 4] = x;
            }
            asm volatile("s_waitcnt lgkmcnt(0)" ::: "memory");
            vsm[PRODB] = k + 8;
            k += 8;
        }
        return;
    }

    // ---------------- consumers: per-lane state tables ----------------
    const int llen = label_lens[b];
    const int i1 = 2 * llen - 1, i2 = 2 * llen;
    int cls[SPL]; float skipf[SPL];
    const int s0 = lane * SPL;
#pragma unroll
    for (int j = 0; j < SPL; ++j) {
        int s = s0 + j;
        int c = CDIM - 1; float sk = 0.f;
        if (s < SDIM && (s & 1)) {
            int kk = s >> 1;
            c = smem[LABSI + kk];
            if (kk >= 1 && smem[LABSI + kk] != smem[LABSI + kk - 1]) sk = 1.f;
        }
        cls[j] = c; skipf[j] = sk;
    }
    const float* ringA = &smf[RINGA];
    const float* ringB = &smf[RINGB];

    if (wv == 0) {
        // ================= alpha (t = 0..m) + combine =================
        float a[SPL], q[4][SPL], ac[SPL];
        int E = 0, Eac = 0;
        float fprev = 0.f;
#pragma unroll
        for (int j = 0; j < SPL; ++j) { a[j] = 0.f; ac[j] = 0.f; }

        while (vsm[PRODA] < 2) __builtin_amdgcn_s_sleep(1);
        asm volatile("" ::: "memory");
#pragma unroll
        for (int j = 0; j < SPL; ++j) {
            q[0][j] = ringA[(0 << 7) + cls[j]];
            q[1][j] = ringA[(1 << 7) + cls[j]];
            q[2][j] = ringA[(2 << 7) + cls[j]];
        }
        if (lane == 0) { a[0] = q[0][0]; a[1] = q[0][1]; }

        int t = 1;
        while (t <= m) {
            vsm[CONSA] = (t >= 2) ? (((t - 2) >> 1) + 1) : 0;
            int need = ((t + 17) >> 1) + 1;
            while (vsm[PRODA] < need) __builtin_amdgcn_s_sleep(1);
            asm volatile("" ::: "memory");
            renorm_alpha(a, E, fprev, lane);
            A_STEP(0) A_STEP(1) A_STEP(2) A_STEP(3)
            renorm_alpha(a, E, fprev, lane);
            A_STEP(4) A_STEP(5) A_STEP(6) A_STEP(7)
            renorm_alpha(a, E, fprev, lane);
            A_STEP(8) A_STEP(9) A_STEP(10) A_STEP(11)
            renorm_alpha(a, E, fprev, lane);
            A_STEP(12) A_STEP(13) A_STEP(14) A_STEP(15)
            t += 16;
        }
        vsm[CONSA] = 1 << 28;
        asm volatile("" ::: "memory");

        while (vsm[BDONE] == 0) __builtin_amdgcn_s_sleep(1);
        asm volatile("" ::: "memory");
        int Eb = smem[BEXPI + lane];
        float dot = 0.f;
#pragma unroll
        for (int j = 0; j < SPL; ++j)
            dot = fmaf(ac[j], smf[BVALS + lane * SPL + j], dot);
        float l2 = (dot > 0.f) ? (log2f(dot) + (float)(Eac + Eb)) : -1e30f;
        float M = l2;
#pragma unroll
        for (int d = 1; d < 64; d <<= 1) M = fmaxf(M, __shfl_xor(M, d, 64));
        float S = exp2f(l2 - M);
#pragma unroll
        for (int d = 1; d < 64; d <<= 1) S += __shfl_xor(S, d, 64);
        if (lane == 0)
            out[b] = -(M + log2f(S)) * 0.69314718055994530942f;
    } else {
        // ================= beta (rows Tbm1 down to m+1) =================
        float bb[SPL], q[4][SPL], bc[SPL];
        int E = 0, Ebc = 0;
        float fnext = 0.f;
#pragma unroll
        for (int j = 0; j < SPL; ++j) {
            int s = s0 + j;
            bb[j] = (s == i1 || s == i2) ? 1.f : 0.f;
            bc[j] = 0.f;
        }
        float skb[SPL];
#pragma unroll
        for (int j = 0; j < 5; ++j) skb[j] = skipf[j + 2];
        skb[5] = (lane == 63) ? 0.f : __shfl_down(skipf[0], 1, 64);
        skb[6] = (lane == 63) ? 0.f : __shfl_down(skipf[1], 1, 64);

        const int t0 = Tbm1;
        const int nb = t0 - m;       // number of steps (>= 1 since m < Tbm1 for Tb >= 2)
        const int scap = nb - 1;
        const int pstart = t0 >> 1;

        while (vsm[PRODB] < 2) __builtin_amdgcn_s_sleep(1);
        asm volatile("" ::: "memory");
#pragma unroll
        for (int j = 0; j < SPL; ++j) {
            q[0][j] = ringB[((t0 & 63) << 7) + cls[j]];
            q[1][j] = ringB[(((t0 - 1) & 63) << 7) + cls[j]];
        }

        int s = 0;
        while (s < nb) {
            int tcur = t0 - s;
            vsm[CONSB] = pstart - ((tcur + 2) >> 1) + 1;
            int need = pstart - ((tcur - 17) >> 1) + 1;
            while (vsm[PRODB] < need) __builtin_amdgcn_s_sleep(1);
            asm volatile("" ::: "memory");
            renorm_beta(bb, E, fnext, lane);
            B_STEP(0) B_STEP(1) B_STEP(2) B_STEP(3)
            renorm_beta(bb, E, fnext, lane);
            B_STEP(4) B_STEP(5) B_STEP(6) B_STEP(7)
            renorm_beta(bb, E, fnext, lane);
            B_STEP(8) B_STEP(9) B_STEP(10) B_STEP(11)
            renorm_beta(bb, E, fnext, lane);
            B_STEP(12) B_STEP(13) B_STEP(14) B_STEP(15)
            s += 16;
        }
        vsm[CONSB] = 1 << 28;
        asm volatile("" ::: "memory");
#pragma unroll
        for (int j = 0; j < SPL; ++j) smf[BVALS + lane * SPL + j] = bc[j];
        smem[BEXPI + lane] = Ebc;
        asm volatile("s_waitcnt lgkmcnt(0)" ::: "memory");
        vsm[BDONE] = 1;
    }
}

extern "C" void kernel_launch(void* const* d_in, const int* in_sizes, int n_in,
                              void* d_out, int out_size, void* d_ws, size_t ws_size,
                              hipStream_t stream) {
    (void)d_ws; (void)ws_size; (void)n_in; (void)out_size;
    const float* y_pred     = (const float*)d_in[0];
    const int*   labels     = (const int*)d_in[1];
    const int*   feat_lens  = (const int*)d_in[2];
    const int*   label_lens = (const int*)d_in[3];
    float* out = (float*)d_out;
    const int B = in_sizes[2];  // 128
    ctc_kernel<<<B, 256, 0, stream>>>(y_pred, labels, feat_lens, label_lens, out);
}